// Round 3
// baseline (3002.470 us; speedup 1.0000x reference)
//
#include <hip/hip_runtime.h>
#include <cstdint>
#include <cstddef>

#define KNB 20
#define NPTS 8192
#define BATCH 2
#define TOTAL (BATCH * NPTS)
#define SPLITS 8
#define CPS (NPTS / SPLITS)   // 1024 candidates per split
#define QB 4                  // queries per attention block

// ---------------------------------------------------------------------------
// K1: pointwise conv 3->64 + relu
// ---------------------------------------------------------------------------
__global__ __launch_bounds__(256) void k_conv(const float* __restrict__ pts,
                                              const float* __restrict__ w,
                                              const float* __restrict__ b,
                                              float* __restrict__ x0) {
  int gid = blockIdx.x * 256 + threadIdx.x;
  if (gid >= TOTAL * 64) return;
  int p = gid >> 6, c = gid & 63;
  float px = pts[p * 3 + 0], py = pts[p * 3 + 1], pz = pts[p * 3 + 2];
  float acc = b[c] + px * w[c] + py * w[64 + c] + pz * w[128 + c];
  x0[gid] = fmaxf(acc, 0.f);
}

// ---------------------------------------------------------------------------
// K2a: partial KNN (unchanged — bit-exact vs lax.top_k).
// ---------------------------------------------------------------------------
__global__ __launch_bounds__(256) void k_knn_part(const float* __restrict__ pts,
                                                  float2* __restrict__ part) {
  __shared__ float sx[CPS], sy[CPS], sz[CPS];
  int tid = threadIdx.x;
  int qb = blockIdx.x;
  int s = blockIdx.y;
  int q = qb * 256 + tid;
  int b = q >> 13;
  const float* pbase = pts + (size_t)b * NPTS * 3;
  const float* cbase = pbase + (size_t)s * CPS * 3;

  for (int c = tid; c < CPS; c += 256) {
    sx[c] = cbase[c * 3 + 0];
    sy[c] = cbase[c * 3 + 1];
    sz[c] = cbase[c * 3 + 2];
  }
  float qx = pts[q * 3 + 0], qy = pts[q * 3 + 1], qz = pts[q * 3 + 2];
  __syncthreads();

  float dist[KNB];
  int id[KNB];
#pragma unroll
  for (int j = 0; j < KNB; j++) { dist[j] = 3.402823466e38f; id[j] = 0; }

  int cid0 = s * CPS;
  for (int c = 0; c < CPS; c++) {
    float dx = qx - sx[c];
    float dy = qy - sy[c];
    float dz = qz - sz[c];
    float d2 = dx * dx + dy * dy + dz * dz;
    if (d2 < dist[KNB - 1]) {
      int cid = cid0 + c;
#pragma unroll
      for (int j = KNB - 1; j >= 0; j--) {
        bool cj = d2 < dist[j];
        bool cjm1 = (j > 0) && (d2 < dist[j - 1]);
        if (cj) {
          dist[j] = cjm1 ? dist[j - 1] : d2;
          id[j]   = cjm1 ? id[j - 1]   : cid;
        }
      }
    }
  }

  float2* dst = part + ((size_t)q * SPLITS + s) * KNB;
#pragma unroll
  for (int j = 0; j < KNB; j++)
    dst[j] = make_float2(dist[j], __int_as_float(id[j]));
}

// ---------------------------------------------------------------------------
// K2b: merge 8 sorted lists of 20 -> top-20 (unchanged).
// ---------------------------------------------------------------------------
__global__ __launch_bounds__(256) void k_knn_merge(const float2* __restrict__ part,
                                                   int* __restrict__ idxbuf) {
  __shared__ float sd[32][SPLITS][KNB];
  __shared__ int   si[32][SPLITS][KNB];
  __shared__ int   sp[32][SPLITS];
  int tid = threadIdx.x;
  int lq = tid >> 3, s = tid & 7;
  int q = blockIdx.x * 32 + lq;

  const float2* src = part + ((size_t)q * SPLITS + s) * KNB;
#pragma unroll
  for (int j = 0; j < KNB; j++) {
    float2 v = src[j];
    sd[lq][s][j] = v.x;
    si[lq][s][j] = __float_as_int(v.y);
  }
  sp[lq][s] = 0;
  __syncthreads();

  if (s == 0) {
    int bq = q >> 13;
    for (int step = 0; step < KNB; step++) {
      float best = 3.402823466e38f;
      int bs = 0, bi = 0;
      for (int s2 = 0; s2 < SPLITS; s2++) {
        int p = sp[lq][s2];
        float d = sd[lq][s2][p];
        if (d < best) { best = d; bs = s2; bi = si[lq][s2][p]; }
      }
      sp[lq][bs]++;
      idxbuf[q * KNB + step] = bq * NPTS + bi;
    }
  }
}

// ---------------------------------------------------------------------------
// K3: qkv GEMM (TOTAL,64) @ (64,192)
// ---------------------------------------------------------------------------
__global__ __launch_bounds__(256) void k_qkv(const float* __restrict__ x,
                                             const float* __restrict__ w,
                                             float* __restrict__ qkv) {
  int gid = blockIdx.x * 256 + threadIdx.x;
  if (gid >= TOTAL * 192) return;
  int p = gid / 192, c = gid % 192;
  const float* xr = x + (size_t)p * 64;
  float acc = 0.f;
#pragma unroll 16
  for (int k = 0; k < 64; k++) acc += xr[k] * w[k * 192 + c];
  qkv[gid] = acc;
}

// ---------------------------------------------------------------------------
// K4: fused attention, QB=4 queries per block (wave wv owns query wv).
//  LDS: s_inp[80][128] (40KB), union{t1[80][64] | aw1 16-row chunk} (20KB).
//  GEMM: acc[4][5][4]/thread; per k4-step 320 FMA : 24 ds_read_b128.
//  vnb is NOT stored: phase C recomputes v + rpe (rpe lives in s_inp[..][64:]).
// ---------------------------------------------------------------------------
__global__ __launch_bounds__(256) void k_attn(
    const float* __restrict__ pos, const float* __restrict__ qkv,
    const int* __restrict__ idxbuf,
    const float* __restrict__ pw1, const float* __restrict__ pb1,
    const float* __restrict__ pw2, const float* __restrict__ pb2,
    const float* __restrict__ aw1, const float* __restrict__ ab1,
    const float* __restrict__ aw2, const float* __restrict__ ab2,
    float* __restrict__ xout) {
  __shared__ float s_inp[QB * KNB][128];   // 40 KB  [row=q*20+n][c]
  __shared__ float s_un[QB * KNB * 64];    // 20 KB  union: t1 | aw1 chunk(16x256)
  __shared__ float s_qi[QB][64];
  __shared__ float s_sim[QB * KNB];
  __shared__ int   s_nb[QB * KNB];

  int i0 = blockIdx.x * QB;
  int tid = threadIdx.x;
  int lane = tid & 63;
  int wv = tid >> 6;

  {
    int q = tid >> 6, c = tid & 63;
    s_qi[q][c] = qkv[(size_t)(i0 + q) * 192 + c];
  }
  if (tid < QB * KNB) {
    int q = tid / KNB, n = tid % KNB;
    s_nb[q * KNB + n] = idxbuf[(i0 + q) * KNB + n];
  }
  __syncthreads();

  // A1: t1[row][h] = relu(rel . pw1[:,h] + pb1[h]),  row = q*20+n
  for (int it = tid; it < QB * KNB * 64; it += 256) {
    int row = it >> 6, h = it & 63;
    int q = row / KNB;
    int g = s_nb[row];
    float rx = pos[(i0 + q) * 3 + 0] - pos[g * 3 + 0];
    float ry = pos[(i0 + q) * 3 + 1] - pos[g * 3 + 1];
    float rz = pos[(i0 + q) * 3 + 2] - pos[g * 3 + 2];
    float a = pb1[h] + rx * pw1[h] + ry * pw1[64 + h] + rz * pw1[128 + h];
    s_un[it] = fmaxf(a, 0.f);
  }
  __syncthreads();

  // A2: rpe[row][c] = t1[row] . pw2[:,c] + pb2[c]; fill inp
  for (int it = tid; it < QB * KNB * 64; it += 256) {
    int row = it >> 6, c = it & 63;
    int q = row / KNB;
    int g = s_nb[row];
    float acc = pb2[c];
    const float* t1r = &s_un[row * 64];
#pragma unroll 8
    for (int h = 0; h < 64; h++) acc += t1r[h] * pw2[h * 64 + c];
    float kv = qkv[(size_t)g * 192 + 64 + c];
    s_inp[row][c] = s_qi[q][c] - kv;
    s_inp[row][64 + c] = acc;
  }

  // B: hidden(80x256) = inp @ aw1, aw1 staged 16 k-rows at a time in s_un.
  int nb0 = 5 * wv;      // wave wv covers neighbors nb0..nb0+4 of EVERY query
  int c0 = 4 * lane;
  float acc[QB][5][4];
#pragma unroll
  for (int q = 0; q < QB; q++)
#pragma unroll
    for (int j = 0; j < 5; j++)
#pragma unroll
      for (int cc = 0; cc < 4; cc++) acc[q][j][cc] = 0.f;

  for (int kc = 0; kc < 128; kc += 16) {
    __syncthreads();  // closes A1/A2 use of s_un (first iter) / prior chunk
    for (int j4 = tid * 4; j4 < 16 * 256; j4 += 1024)
      *(float4*)&s_un[j4] = *(const float4*)&aw1[kc * 256 + j4];
    __syncthreads();
#pragma unroll
    for (int k4 = 0; k4 < 16; k4 += 4) {
      float4 a0 = *(float4*)&s_un[(k4 + 0) * 256 + c0];
      float4 a1 = *(float4*)&s_un[(k4 + 1) * 256 + c0];
      float4 a2 = *(float4*)&s_un[(k4 + 2) * 256 + c0];
      float4 a3 = *(float4*)&s_un[(k4 + 3) * 256 + c0];
#pragma unroll
      for (int q = 0; q < QB; q++)
#pragma unroll
        for (int j = 0; j < 5; j++) {
          float4 iv = *(float4*)&s_inp[q * KNB + nb0 + j][kc + k4];
          acc[q][j][0] += iv.x * a0.x + iv.y * a1.x + iv.z * a2.x + iv.w * a3.x;
          acc[q][j][1] += iv.x * a0.y + iv.y * a1.y + iv.z * a2.y + iv.w * a3.y;
          acc[q][j][2] += iv.x * a0.z + iv.y * a1.z + iv.z * a2.z + iv.w * a3.z;
          acc[q][j][3] += iv.x * a0.w + iv.y * a1.w + iv.z * a2.w + iv.w * a3.w;
        }
    }
  }

  // epilogue: relu(+ab1) . aw2, butterfly-reduce 64 lanes -> sim
  float4 b1 = *(const float4*)&ab1[c0];
  float4 w2 = *(const float4*)&aw2[c0];
  float ab2v = ab2[0];
#pragma unroll
  for (int q = 0; q < QB; q++)
#pragma unroll
    for (int j = 0; j < 5; j++) {
      float s = fmaxf(acc[q][j][0] + b1.x, 0.f) * w2.x +
                fmaxf(acc[q][j][1] + b1.y, 0.f) * w2.y +
                fmaxf(acc[q][j][2] + b1.z, 0.f) * w2.z +
                fmaxf(acc[q][j][3] + b1.w, 0.f) * w2.w;
#pragma unroll
      for (int off = 32; off > 0; off >>= 1) s += __shfl_xor(s, off);
      if (lane == 0) s_sim[q * KNB + nb0 + j] = s + ab2v;
    }
  __syncthreads();

  // C: softmax over K=20, out = sum attn * (v_gather + rpe)
  {
    int q = tid >> 6, c = tid & 63;
    float mx = -3.402823466e38f;
#pragma unroll
    for (int n = 0; n < KNB; n++) mx = fmaxf(mx, s_sim[q * KNB + n]);
    float e[KNB];
    float sum = 0.f;
#pragma unroll
    for (int n = 0; n < KNB; n++) {
      e[n] = expf(s_sim[q * KNB + n] - mx);
      sum += e[n];
    }
    float inv = 1.f / sum;
    float o = 0.f;
#pragma unroll
    for (int n = 0; n < KNB; n++) {
      int g = s_nb[q * KNB + n];
      float vnb = qkv[(size_t)g * 192 + 128 + c] + s_inp[q * KNB + n][64 + c];
      o += (e[n] * inv) * vnb;
    }
    xout[(size_t)(i0 + q) * 64 + c] = o;
  }
}

// ---------------------------------------------------------------------------
// K5: global max-pool + fc1 + fc3 (unchanged)
// ---------------------------------------------------------------------------
__global__ __launch_bounds__(256) void k_final(const float* __restrict__ x,
                                               const float* __restrict__ fc1w,
                                               const float* __restrict__ fc1b,
                                               const float* __restrict__ fc3w,
                                               const float* __restrict__ fc3b,
                                               float* __restrict__ out) {
  __shared__ float red[4][64];
  __shared__ float m[64];
  __shared__ float h1[32];
  int b = blockIdx.x;
  int tid = threadIdx.x;
  int c = tid & 63, pg = tid >> 6;
  float mx = -3.402823466e38f;
  for (int p = pg; p < NPTS; p += 4)
    mx = fmaxf(mx, x[((size_t)b * NPTS + p) * 64 + c]);
  red[pg][c] = mx;
  __syncthreads();
  if (tid < 64)
    m[c] = fmaxf(fmaxf(red[0][c], red[1][c]), fmaxf(red[2][c], red[3][c]));
  __syncthreads();
  if (tid < 32) {
    float a = fc1b[tid];
#pragma unroll 8
    for (int k = 0; k < 64; k++) a += m[k] * fc1w[k * 32 + tid];
    h1[tid] = fmaxf(a, 0.f);
  }
  __syncthreads();
  if (tid < 3) {
    float a = fc3b[tid];
#pragma unroll
    for (int k = 0; k < 32; k++) a += h1[k] * fc3w[k * 3 + tid];
    out[b * 3 + tid] = a;
  }
}

// ---------------------------------------------------------------------------
extern "C" void kernel_launch(void* const* d_in, const int* in_sizes, int n_in,
                              void* d_out, int out_size, void* d_ws,
                              size_t ws_size, hipStream_t stream) {
  const float* pts    = (const float*)d_in[0];
  const float* conv_w = (const float*)d_in[1];
  const float* conv_b = (const float*)d_in[2];
  const float* fc1w = (const float*)d_in[21];
  const float* fc1b = (const float*)d_in[22];
  const float* fc3w = (const float*)d_in[23];
  const float* fc3b = (const float*)d_in[24];
  float* outp = (float*)d_out;

  char* ws = (char*)d_ws;
  float*  x0   = (float*) (ws);
  int*    idx  = (int*)   (ws + (size_t)4 * 1048576);
  float2* part = (float2*)(ws + (size_t)6 * 1048576);
  float*  qkv  = (float*) (ws + (size_t)6 * 1048576);   // reuses part region
  float*  x1   = (float*) (ws + (size_t)19 * 1048576);
  float*  x2   = (float*) (ws + (size_t)19 * 1048576 + 4194304);

  k_conv<<<(TOTAL * 64 + 255) / 256, 256, 0, stream>>>(pts, conv_w, conv_b, x0);
  k_knn_part<<<dim3(TOTAL / 256, SPLITS), 256, 0, stream>>>(pts, part);
  k_knn_merge<<<TOTAL / 32, 256, 0, stream>>>(part, idx);

  // layer 1
  {
    const float* qkvw = (const float*)d_in[3];
    k_qkv<<<(TOTAL * 192 + 255) / 256, 256, 0, stream>>>(x0, qkvw, qkv);
    k_attn<<<TOTAL / QB, 256, 0, stream>>>(
        pts, qkv, idx, (const float*)d_in[4], (const float*)d_in[5],
        (const float*)d_in[6], (const float*)d_in[7], (const float*)d_in[8],
        (const float*)d_in[9], (const float*)d_in[10], (const float*)d_in[11],
        x1);
  }
  // layer 2
  {
    const float* qkvw = (const float*)d_in[12];
    k_qkv<<<(TOTAL * 192 + 255) / 256, 256, 0, stream>>>(x1, qkvw, qkv);
    k_attn<<<TOTAL / QB, 256, 0, stream>>>(
        pts, qkv, idx, (const float*)d_in[13], (const float*)d_in[14],
        (const float*)d_in[15], (const float*)d_in[16], (const float*)d_in[17],
        (const float*)d_in[18], (const float*)d_in[19], (const float*)d_in[20],
        x2);
  }
  k_final<<<BATCH, 256, 0, stream>>>(x2, fc1w, fc1b, fc3w, fc3b, outp);
}